// Round 9
// baseline (154.238 us; speedup 1.0000x reference)
//
#include <hip/hip_runtime.h>

// Problem dims
#define NB   4
#define CIN  256
#define MID  64
#define HW   4096
#define NBLK 128   // n-tiles of 32 rows

typedef __attribute__((ext_vector_type(8))) short bfrag8;   // 8 bf16 (4 VGPR) MFMA operand
typedef __attribute__((ext_vector_type(4))) float facc4;    // MFMA accumulator

// Workspace layout (bytes), ~30.2 MB
constexpr size_t OFF_FHI   = 0;          // [B][4096][64] bf16
constexpr size_t OFF_FLO   = 2097152;    // [B][4096][64] bf16
constexpr size_t OFF_WHI   = 4194304;    // [192][256] bf16
constexpr size_t OFF_WLO   = 4292608;    // [192][256] bf16
constexpr size_t OFF_BEFF  = 4390912;    // [192] f32 (pad 1KB)
constexpr size_t OFF_W2HI  = 4391936;    // [B][256][64] bf16
constexpr size_t OFF_W2LO  = 4523008;    // [B][256][64] bf16
constexpr size_t OFF_MPART = 4654080;    // [B][128][192][64] f32  (M|F2|GF rows)
constexpr size_t OFF_TPART = 29819904;   // [B][128][64] f32
constexpr size_t OFF_MFIN  = 29950976;   // [B][192][64] f32
constexpr size_t OFF_TFIN  = 30147584;   // [B][64] f32

__device__ __forceinline__ unsigned short f2bf(float f) {
    union { float f; unsigned u; } v; v.f = f;
    unsigned r = v.u + 0x7FFF + ((v.u >> 16) & 1);  // RNE
    return (unsigned short)(r >> 16);
}
__device__ __forceinline__ float bf2f(unsigned short h) {
    union { unsigned u; float f; } v; v.u = ((unsigned)h) << 16;
    return v.f;
}
__device__ __forceinline__ void split_bf(float v, unsigned short& hi, unsigned short& lo) {
    hi = f2bf(v);
    lo = f2bf(v - bf2f(hi));
}

// K0: fold BN into conv weights -> hi/lo bf16 [o][c]; beff f32  (once; L2-resident after)
__global__ void k_weff(const float* __restrict__ Wf, const float* __restrict__ bf,
                       const float* __restrict__ gf, const float* __restrict__ btf,
                       const float* __restrict__ mf, const float* __restrict__ vf,
                       const float* __restrict__ Wg, const float* __restrict__ bg,
                       const float* __restrict__ gg, const float* __restrict__ btg,
                       const float* __restrict__ mg, const float* __restrict__ vg,
                       const float* __restrict__ Wh, const float* __restrict__ bh,
                       unsigned short* __restrict__ whi, unsigned short* __restrict__ wlo,
                       float* __restrict__ beff) {
    const int o = blockIdx.x;   // 0..191
    const int c = threadIdx.x;  // 0..255
    float w, sh;
    if (o < 64) {
        float inv = gf[o] * rsqrtf(vf[o] + 1e-5f);
        w  = Wf[o * CIN + c] * inv;
        sh = bf[o] * inv + btf[o] - mf[o] * inv;
    } else if (o < 128) {
        int oo = o - 64;
        float inv = gg[oo] * rsqrtf(vg[oo] + 1e-5f);
        w  = Wg[oo * CIN + c] * inv;
        sh = bg[oo] * inv + btg[oo] - mg[oo] * inv;
    } else {
        int oo = o - 128;
        w  = Wh[oo * CIN + c];
        sh = bh[oo];
    }
    unsigned short hi, lo; split_bf(w, hi, lo);
    whi[o * CIN + c] = hi;
    wlo[o * CIN + c] = lo;
    if (c == 0) beff[o] = sh;
}

// K1 (mega): 32 n x 192 o per block. split-bf16 MFMA.
// Epilogue: fhi/flo bf16 (f), partials of t = g.v0, M = g h^T, F2 = f f^T, GF = g f^T.
__launch_bounds__(512)
__global__ void k_fgh2(const float* __restrict__ x,
                       const unsigned short* __restrict__ whi_g,
                       const unsigned short* __restrict__ wlo_g,
                       const float* __restrict__ beff,
                       const float* __restrict__ v0,
                       unsigned short* __restrict__ fhi, unsigned short* __restrict__ flo,
                       float* __restrict__ tpart, float* __restrict__ mpart) {
    __shared__ float beffs[192];
    __shared__ float v0ls[32];
    __shared__ unsigned short xh[32][72], xl[32][72];
    __shared__ char wbuf[55296];   // wh[192][72], wl[192][72]; aliased in epilogue
    unsigned short (*wh)[72] = (unsigned short(*)[72])wbuf;
    unsigned short (*wl)[72] = (unsigned short(*)[72])(wbuf + 192 * 72 * 2);

    const int nb = blockIdx.x, b = blockIdx.y;
    const int n0 = nb * 32;
    const int tid = threadIdx.x, l = tid & 63, w = tid >> 6;  // 8 waves
    const int wo = w >> 1, wn = w & 1;                        // 4 o-groups(48) x 2 n-halves(16)
    const int lr = l & 15, lk = l >> 4;

    if (tid < 192) beffs[tid] = beff[tid];
    if (tid < 32)  v0ls[tid] = v0[(size_t)b * HW + n0 + tid];

    facc4 acc[3];
    #pragma unroll
    for (int j = 0; j < 3; ++j) acc[j] = (facc4){0.f, 0.f, 0.f, 0.f};

    for (int kc = 0; kc < 4; ++kc) {
        const int c0 = kc * 64;
        {   // stage x chunk [64c][32n] f32 -> xh/xl [n][c]
            const int c = tid >> 3, n4 = (tid & 7) * 4;
            const float* xr = x + ((size_t)(b * CIN + c0 + c)) * HW + n0 + n4;
            float4 v = *(const float4*)xr;
            #pragma unroll
            for (int i = 0; i < 4; ++i) {
                unsigned short hi, lo; split_bf((&v.x)[i], hi, lo);
                xh[n4 + i][c] = hi; xl[n4 + i][c] = lo;
            }
        }
        {   // stage w chunk [192o][64c] bf16 hi/lo (L2-resident)
            #pragma unroll
            for (int k = 0; k < 3; ++k) {
                const int id = tid + k * 512;
                const int orow = id >> 3, cs = id & 7;
                *(bfrag8*)&wh[orow][cs * 8] = *(const bfrag8*)(whi_g + orow * CIN + c0 + cs * 8);
                *(bfrag8*)&wl[orow][cs * 8] = *(const bfrag8*)(wlo_g + orow * CIN + c0 + cs * 8);
            }
        }
        __syncthreads();
        #pragma unroll
        for (int ks = 0; ks < 2; ++ks) {
            bfrag8 ah = *(const bfrag8*)&xh[wn * 16 + lr][ks * 32 + lk * 8];
            bfrag8 al = *(const bfrag8*)&xl[wn * 16 + lr][ks * 32 + lk * 8];
            #pragma unroll
            for (int so = 0; so < 3; ++so) {
                bfrag8 bh8 = *(const bfrag8*)&wh[wo * 48 + so * 16 + lr][ks * 32 + lk * 8];
                bfrag8 bl8 = *(const bfrag8*)&wl[wo * 48 + so * 16 + lr][ks * 32 + lk * 8];
                acc[so] = __builtin_amdgcn_mfma_f32_16x16x32_bf16(ah, bh8, acc[so], 0, 0, 0);
                acc[so] = __builtin_amdgcn_mfma_f32_16x16x32_bf16(ah, bl8, acc[so], 0, 0, 0);
                acc[so] = __builtin_amdgcn_mfma_f32_16x16x32_bf16(al, bh8, acc[so], 0, 0, 0);
            }
        }
        __syncthreads();
    }

    // ---- epilogue: mls [32 n][192 o] f32 (aliases wbuf) + reduce scratch ----
    float (*mls)[200] = (float(*)[200])wbuf;            // 25.6 KB  (cols: 0-63 f, 64-127 g, 128-191 h)
    float (*tred)[64] = (float(*)[64])(wbuf + 25600);   // [8][64] 2 KB

    #pragma unroll
    for (int so = 0; so < 3; ++so) {
        const int o = wo * 48 + so * 16 + lr;
        const float bias = beffs[o];
        const bool rl = (o < 128);   // relu on f,g only
        #pragma unroll
        for (int r = 0; r < 4; ++r) {
            const int nn = wn * 16 + lk * 4 + r;
            float v = acc[so][r] + bias;
            if (rl) v = fmaxf(v, 0.0f);
            mls[nn][o] = v;
            if (o < 64) {
                unsigned short hi, lo; split_bf(v, hi, lo);
                fhi[((size_t)(b * HW) + n0 + nn) * MID + o] = hi;
                flo[((size_t)(b * HW) + n0 + nn) * MID + o] = lo;
            }
        }
    }
    __syncthreads();

    {   // t partials: t[c] += sum_n g[n][c] * v0[n]
        const int c = tid & 63, ng = tid >> 6;
        float tp = 0.f;
        #pragma unroll
        for (int i = 0; i < 4; ++i) {
            const int nn = ng * 4 + i;
            tp = fmaf(mls[nn][64 + c], v0ls[nn], tp);
        }
        tred[ng][c] = tp;
    }
    {   // M / F2 / GF partials (rows cp, cols cc): M=g h^T, F2=f f^T, GF=g f^T
        const int tcp = tid >> 4, tc = tid & 15;
        const int cp = tcp * 2, cc = tc * 4;
        float mM[2][4], mF[2][4], mG[2][4];
        #pragma unroll
        for (int i = 0; i < 2; ++i)
            #pragma unroll
            for (int j = 0; j < 4; ++j) { mM[i][j] = 0.f; mF[i][j] = 0.f; mG[i][j] = 0.f; }
        for (int nn = 0; nn < 32; ++nn) {
            const float f0 = mls[nn][cp], f1 = mls[nn][cp + 1];
            const float g0 = mls[nn][64 + cp], g1 = mls[nn][64 + cp + 1];
            float4 fc = *(const float4*)&mls[nn][cc];
            float4 hc = *(const float4*)&mls[nn][128 + cc];
            #pragma unroll
            for (int j = 0; j < 4; ++j) {
                const float fcj = (&fc.x)[j], hcj = (&hc.x)[j];
                mM[0][j] = fmaf(g0, hcj, mM[0][j]);  mM[1][j] = fmaf(g1, hcj, mM[1][j]);
                mF[0][j] = fmaf(f0, fcj, mF[0][j]);  mF[1][j] = fmaf(f1, fcj, mF[1][j]);
                mG[0][j] = fmaf(g0, fcj, mG[0][j]);  mG[1][j] = fmaf(g1, fcj, mG[1][j]);
            }
        }
        const size_t base = ((size_t)(b * NBLK) + nb) * (192 * 64);
        #pragma unroll
        for (int i = 0; i < 2; ++i) {
            *(float4*)&mpart[base + (size_t)(0   + cp + i) * 64 + cc] = make_float4(mM[i][0], mM[i][1], mM[i][2], mM[i][3]);
            *(float4*)&mpart[base + (size_t)(64  + cp + i) * 64 + cc] = make_float4(mF[i][0], mF[i][1], mF[i][2], mF[i][3]);
            *(float4*)&mpart[base + (size_t)(128 + cp + i) * 64 + cc] = make_float4(mG[i][0], mG[i][1], mG[i][2], mG[i][3]);
        }
    }
    __syncthreads();
    if (tid < 64) {
        float s = 0.f;
        #pragma unroll
        for (int g = 0; g < 8; ++g) s += tred[g][tid];
        tpart[((size_t)(b * NBLK) + nb) * 64 + tid] = s;
    }
}

// K2: reduce partials: Mfin[b][192][64] (M|F2|GF) and tfin[b][64]
__launch_bounds__(256)
__global__ void k_red(const float* __restrict__ mpart, const float* __restrict__ tpart,
                      float* __restrict__ Mfin, float* __restrict__ tfin) {
    __shared__ float tred2[4][64];
    const int rb = blockIdx.x, b = blockIdx.y;   // rb: 0..23, 8 rows each
    const int tid = threadIdx.x;
    const int c = tid & 63, rq = tid >> 6;
    #pragma unroll
    for (int p = 0; p < 2; ++p) {
        const int rr = rb * 8 + p * 4 + rq;
        float s = 0.f;
        for (int nb = 0; nb < NBLK; ++nb)
            s += mpart[((size_t)(b * NBLK) + nb) * (192 * 64) + (size_t)rr * 64 + c];
        Mfin[((size_t)(b * 192) + rr) * 64 + c] = s;
    }
    if (rb == 0) {
        float s = 0.f;
        #pragma unroll 8
        for (int i = 0; i < 32; ++i)
            s += tpart[((size_t)(b * NBLK) + rq * 32 + i) * 64 + c];
        tred2[rq][c] = s;
        __syncthreads();
        if (tid < 64) tfin[b * 64 + tid] = tred2[0][tid] + tred2[1][tid] + tred2[2][tid] + tred2[3][tid];
    }
}

// K3: u = F2 t, w = GF t, s = (u.w)/(t.u); w2[b][o][cp0..+7] = (1/s) Wv M^T  (hi/lo bf16)
__launch_bounds__(256)
__global__ void k_w2s(const float* __restrict__ Wv, const float* __restrict__ Mfin,
                      const float* __restrict__ tfin,
                      unsigned short* __restrict__ w2hi, unsigned short* __restrict__ w2lo) {
    __shared__ float ts[64], uu[64], ww[64];
    __shared__ float Mc[8][64];
    __shared__ float svs;
    const int cp0 = blockIdx.x * 8, b = blockIdx.y;
    const int tid = threadIdx.x;
    if (tid < 64) ts[tid] = tfin[b * 64 + tid];
    {   // stage M rows cp0..cp0+7
        const int e0 = tid, e1 = tid + 256;
        Mc[e0 >> 6][e0 & 63] = Mfin[((size_t)(b * 192) + cp0 + (e0 >> 6)) * 64 + (e0 & 63)];
        Mc[e1 >> 6][e1 & 63] = Mfin[((size_t)(b * 192) + cp0 + (e1 >> 6)) * 64 + (e1 & 63)];
    }
    __syncthreads();
    if (tid < 128) {
        const int i = tid & 63;
        const float* row = Mfin + ((size_t)(b * 192) + (tid < 64 ? 64 : 128) + i) * 64;
        float a = 0.f;
        #pragma unroll
        for (int u = 0; u < 16; ++u) {
            float4 r4 = *(const float4*)(row + u * 4);
            a = fmaf(r4.x, ts[u * 4 + 0], a);
            a = fmaf(r4.y, ts[u * 4 + 1], a);
            a = fmaf(r4.z, ts[u * 4 + 2], a);
            a = fmaf(r4.w, ts[u * 4 + 3], a);
        }
        if (tid < 64) uu[i] = a; else ww[i] = a;
    }
    __syncthreads();
    if (tid < 64) {
        float num = uu[tid] * ww[tid];
        float den = ts[tid] * uu[tid];
        #pragma unroll
        for (int off = 32; off > 0; off >>= 1) {
            num += __shfl_down(num, off);
            den += __shfl_down(den, off);
        }
        if (tid == 0) svs = num / den;
    }
    __syncthreads();
    const float inv_s = 1.0f / svs;
    const int o = tid;
    float wv[64];
    #pragma unroll
    for (int u = 0; u < 16; ++u) {
        float4 w4 = *(const float4*)(Wv + o * MID + u * 4);
        wv[u * 4 + 0] = w4.x; wv[u * 4 + 1] = w4.y; wv[u * 4 + 2] = w4.z; wv[u * 4 + 3] = w4.w;
    }
    unsigned short rh[8] __attribute__((aligned(16)));
    unsigned short rl[8] __attribute__((aligned(16)));
    #pragma unroll
    for (int j = 0; j < 8; ++j) {
        float a = 0.f;
        #pragma unroll
        for (int c = 0; c < 64; ++c) a = fmaf(wv[c], Mc[j][c], a);
        split_bf(a * inv_s, rh[j], rl[j]);
    }
    const size_t base = ((size_t)(b * CIN) + o) * MID + cp0;
    *(bfrag8*)(w2hi + base) = *(const bfrag8*)rh;
    *(bfrag8*)(w2lo + base) = *(const bfrag8*)rl;
}

// K4: out[b][o][n] = x + bv[o] + sum_cp w2[o][cp] f[n][cp]   via split-bf16 MFMA, D[o][n]
__launch_bounds__(256)
__global__ void k_out(const float* __restrict__ x,
                      const unsigned short* __restrict__ fhi, const unsigned short* __restrict__ flo,
                      const unsigned short* __restrict__ w2hi, const unsigned short* __restrict__ w2lo,
                      const float* __restrict__ bv, float* __restrict__ out) {
    __shared__ unsigned short fh[64][72], fl[64][72], wh[64][72], wl[64][72];
    const int n0 = blockIdx.x * 64;
    const int o0 = blockIdx.y * 64;
    const int b  = blockIdx.z;
    const int tid = threadIdx.x, l = tid & 63, w = tid >> 6;
    const int wo = w >> 1, wn = w & 1;
    const int lr = l & 15, lk = l >> 4;
    #pragma unroll
    for (int i = 0; i < 2; ++i) {
        int ch = tid + i * 256;
        int row = ch >> 3, cs = ch & 7;
        const size_t fsrc = ((size_t)(b * HW) + n0 + row) * MID + cs * 8;
        const size_t wsrc = ((size_t)(b * CIN) + o0 + row) * MID + cs * 8;
        *(bfrag8*)&fh[row][cs * 8] = *(const bfrag8*)(fhi + fsrc);
        *(bfrag8*)&fl[row][cs * 8] = *(const bfrag8*)(flo + fsrc);
        *(bfrag8*)&wh[row][cs * 8] = *(const bfrag8*)(w2hi + wsrc);
        *(bfrag8*)&wl[row][cs * 8] = *(const bfrag8*)(w2lo + wsrc);
    }
    __syncthreads();
    facc4 acc[2][2];   // [so][sn]
    #pragma unroll
    for (int i = 0; i < 2; ++i)
        #pragma unroll
        for (int j = 0; j < 2; ++j) acc[i][j] = (facc4){0.f, 0.f, 0.f, 0.f};
    #pragma unroll
    for (int ks = 0; ks < 2; ++ks) {
        bfrag8 ah[2], al[2], bh[2], bl[2];
        #pragma unroll
        for (int s = 0; s < 2; ++s) {
            ah[s] = *(const bfrag8*)&wh[wo * 32 + s * 16 + lr][ks * 32 + lk * 8];
            al[s] = *(const bfrag8*)&wl[wo * 32 + s * 16 + lr][ks * 32 + lk * 8];
            bh[s] = *(const bfrag8*)&fh[wn * 32 + s * 16 + lr][ks * 32 + lk * 8];
            bl[s] = *(const bfrag8*)&fl[wn * 32 + s * 16 + lr][ks * 32 + lk * 8];
        }
        #pragma unroll
        for (int so = 0; so < 2; ++so)
            #pragma unroll
            for (int sn = 0; sn < 2; ++sn) {
                acc[so][sn] = __builtin_amdgcn_mfma_f32_16x16x32_bf16(ah[so], bh[sn], acc[so][sn], 0, 0, 0);
                acc[so][sn] = __builtin_amdgcn_mfma_f32_16x16x32_bf16(ah[so], bl[sn], acc[so][sn], 0, 0, 0);
                acc[so][sn] = __builtin_amdgcn_mfma_f32_16x16x32_bf16(al[so], bh[sn], acc[so][sn], 0, 0, 0);
            }
    }
    #pragma unroll
    for (int so = 0; so < 2; ++so)
        #pragma unroll
        for (int r = 0; r < 4; ++r) {
            const int o = o0 + wo * 32 + so * 16 + lk * 4 + r;
            const float bias = bv[o];
            #pragma unroll
            for (int sn = 0; sn < 2; ++sn) {
                const int n = n0 + wn * 32 + sn * 16 + lr;
                const size_t idx = ((size_t)(b * CIN) + o) * HW + n;
                out[idx] = x[idx] + bias + acc[so][sn][r];
            }
        }
}

extern "C" void kernel_launch(void* const* d_in, const int* in_sizes, int n_in,
                              void* d_out, int out_size, void* d_ws, size_t ws_size,
                              hipStream_t stream) {
    const float* x   = (const float*)d_in[0];
    const float* Wf  = (const float*)d_in[1];
    const float* bf  = (const float*)d_in[2];
    const float* gaf = (const float*)d_in[3];
    const float* bef = (const float*)d_in[4];
    const float* mef = (const float*)d_in[5];
    const float* vaf = (const float*)d_in[6];
    const float* Wg  = (const float*)d_in[7];
    const float* bg  = (const float*)d_in[8];
    const float* gag = (const float*)d_in[9];
    const float* beg = (const float*)d_in[10];
    const float* meg = (const float*)d_in[11];
    const float* vag = (const float*)d_in[12];
    const float* Wh  = (const float*)d_in[13];
    const float* bh  = (const float*)d_in[14];
    const float* Wv  = (const float*)d_in[15];
    const float* bv  = (const float*)d_in[16];
    const float* v0  = (const float*)d_in[17];
    float* out = (float*)d_out;
    char* ws = (char*)d_ws;

    unsigned short* fhi  = (unsigned short*)(ws + OFF_FHI);
    unsigned short* flo  = (unsigned short*)(ws + OFF_FLO);
    unsigned short* whi  = (unsigned short*)(ws + OFF_WHI);
    unsigned short* wlo  = (unsigned short*)(ws + OFF_WLO);
    float*          beff = (float*)(ws + OFF_BEFF);
    unsigned short* w2hi = (unsigned short*)(ws + OFF_W2HI);
    unsigned short* w2lo = (unsigned short*)(ws + OFF_W2LO);
    float*          mpart= (float*)(ws + OFF_MPART);
    float*          tpart= (float*)(ws + OFF_TPART);
    float*          Mfin = (float*)(ws + OFF_MFIN);
    float*          tfin = (float*)(ws + OFF_TFIN);

    k_weff<<<192, CIN, 0, stream>>>(Wf, bf, gaf, bef, mef, vaf,
                                    Wg, bg, gag, beg, meg, vag,
                                    Wh, bh, whi, wlo, beff);
    k_fgh2<<<dim3(NBLK, NB), 512, 0, stream>>>(x, whi, wlo, beff, v0,
                                               fhi, flo, tpart, mpart);
    k_red <<<dim3(24, NB), 256, 0, stream>>>(mpart, tpart, Mfin, tfin);
    k_w2s <<<dim3(8, NB), 256, 0, stream>>>(Wv, Mfin, tfin, w2hi, w2lo);
    k_out <<<dim3(HW / 64, CIN / 64, NB), 256, 0, stream>>>(x, fhi, flo, w2hi, w2lo, bv, out);
}

// Round 11
// 133.241 us; speedup vs baseline: 1.1576x; 1.1576x over previous
//
#include <hip/hip_runtime.h>

// Problem dims
#define NB   4
#define CIN  256
#define MID  64
#define HW   4096

typedef __attribute__((ext_vector_type(8))) short bfrag8;   // 8 bf16 (4 VGPR) MFMA operand
typedef __attribute__((ext_vector_type(4))) short svec4;    // 8B bf16 store
typedef __attribute__((ext_vector_type(4))) float facc4;    // MFMA accumulator

// Workspace layout (bytes), ~17.4 MB
constexpr size_t OFF_FGHT  = 0;          // [B][4096][128] f32 (f,g)
constexpr size_t OFF_FHI   = 8388608;    // [B][4096][64] bf16
constexpr size_t OFF_FLO   = 10485760;   // [B][4096][64] bf16
constexpr size_t OFF_WHI   = 12582912;   // [192][256] bf16
constexpr size_t OFF_WLO   = 12681216;   // [192][256] bf16
constexpr size_t OFF_BEFF  = 12779520;   // [192] f32 (pad 1KB)
constexpr size_t OFF_W2HI  = 12780544;   // [B][256][64] bf16
constexpr size_t OFF_W2LO  = 12911616;   // [B][256][64] bf16
constexpr size_t OFF_MPART = 13042688;   // [B][64][64][64] f32
constexpr size_t OFF_TPART = 17236992;   // [B][64][64] f32
constexpr size_t OFF_FGVUP = 17302528;   // [B][64][128] f32
constexpr size_t OFF_NSQP  = 17433600;   // [B][64] f32

__device__ __forceinline__ unsigned short f2bf(float f) {
    union { float f; unsigned u; } v; v.f = f;
    unsigned r = v.u + 0x7FFF + ((v.u >> 16) & 1);  // RNE
    return (unsigned short)(r >> 16);
}
__device__ __forceinline__ float bf2f(unsigned short h) {
    union { unsigned u; float f; } v; v.u = ((unsigned)h) << 16;
    return v.f;
}
__device__ __forceinline__ void split_bf(float v, unsigned short& hi, unsigned short& lo) {
    hi = f2bf(v);
    lo = f2bf(v - bf2f(hi));
}

// K0: fold BN into conv weights -> hi/lo bf16 [o][c]; beff f32
__global__ void k_weff(const float* __restrict__ Wf, const float* __restrict__ bf,
                       const float* __restrict__ gf, const float* __restrict__ btf,
                       const float* __restrict__ mf, const float* __restrict__ vf,
                       const float* __restrict__ Wg, const float* __restrict__ bg,
                       const float* __restrict__ gg, const float* __restrict__ btg,
                       const float* __restrict__ mg, const float* __restrict__ vg,
                       const float* __restrict__ Wh, const float* __restrict__ bh,
                       unsigned short* __restrict__ whi, unsigned short* __restrict__ wlo,
                       float* __restrict__ beff) {
    const int o = blockIdx.x;   // 0..191
    const int c = threadIdx.x;  // 0..255
    float w, sh;
    if (o < 64) {
        float inv = gf[o] * rsqrtf(vf[o] + 1e-5f);
        w  = Wf[o * CIN + c] * inv;
        sh = bf[o] * inv + btf[o] - mf[o] * inv;
    } else if (o < 128) {
        int oo = o - 64;
        float inv = gg[oo] * rsqrtf(vg[oo] + 1e-5f);
        w  = Wg[oo * CIN + c] * inv;
        sh = bg[oo] * inv + btg[oo] - mg[oo] * inv;
    } else {
        int oo = o - 128;
        w  = Wh[oo * CIN + c];
        sh = bh[oo];
    }
    unsigned short hi, lo; split_bf(w, hi, lo);
    whi[o * CIN + c] = hi;
    wlo[o * CIN + c] = lo;
    if (c == 0) beff[o] = sh;
}

// K1 (mega, proven 138.3 config): 64 n x 192 o per block; split-bf16 MFMA.
// Epilogue: fghT f32 (f,g), fhi/flo bf16 (f), t-partials (tpart) + M-partials from in-LDS g,h.
__launch_bounds__(512)
__global__ void k_fgh2(const float* __restrict__ x,
                       const unsigned short* __restrict__ whi_g,
                       const unsigned short* __restrict__ wlo_g,
                       const float* __restrict__ beff,
                       const float* __restrict__ v0,
                       float* __restrict__ fghT,
                       unsigned short* __restrict__ fhi,
                       unsigned short* __restrict__ flo,
                       float* __restrict__ tpart, float* __restrict__ mpart) {
    __shared__ unsigned short xh[64][72], xl[64][72];   // 18.4 KB
    __shared__ char wbuf[55296];                        // wh[192][72], wl[192][72]; aliased in epilogue
    unsigned short (*wh)[72] = (unsigned short(*)[72])wbuf;
    unsigned short (*wl)[72] = (unsigned short(*)[72])(wbuf + 192 * 72 * 2);

    const int nb = blockIdx.x, b = blockIdx.y;
    const int n0 = nb * 64;
    const int tid = threadIdx.x, l = tid & 63, w = tid >> 6;  // 8 waves
    const int wo = w >> 1, wn = w & 1;                        // 4 o-groups(48) x 2 n-halves(32)
    const int lr = l & 15, lk = l >> 4;
    facc4 acc[2][3];
    #pragma unroll
    for (int i = 0; i < 2; ++i)
        #pragma unroll
        for (int j = 0; j < 3; ++j) acc[i][j] = (facc4){0.f, 0.f, 0.f, 0.f};

    const int cr = tid >> 4, nq = tid & 15;   // x-stage: c-pair, n-quad

    for (int kc = 0; kc < 4; ++kc) {
        const int c0 = kc * 64;
        {   // stage x chunk [64c][64n] f32 -> xh/xl [n][c] (split in-flight)
            const float* xr = x + ((size_t)(b * CIN + c0 + cr * 2)) * HW + n0 + nq * 4;
            float4 va = *(const float4*)xr;
            float4 vb = *(const float4*)(xr + HW);
            #pragma unroll
            for (int i = 0; i < 4; ++i) {
                float fa = (&va.x)[i], fb = (&vb.x)[i];
                unsigned short ha, la, hb, lb;
                split_bf(fa, ha, la);
                split_bf(fb, hb, lb);
                const int n = nq * 4 + i;
                *(unsigned int*)&xh[n][cr * 2] = (unsigned int)ha | ((unsigned int)hb << 16);
                *(unsigned int*)&xl[n][cr * 2] = (unsigned int)la | ((unsigned int)lb << 16);
            }
        }
        {   // stage w chunk [192o][64c] bf16 hi/lo (L2-resident)
            #pragma unroll
            for (int k = 0; k < 3; ++k) {
                const int id = tid + k * 512;
                const int orow = id >> 3, cs = id & 7;
                *(bfrag8*)&wh[orow][cs * 8] = *(const bfrag8*)(whi_g + orow * CIN + c0 + cs * 8);
                *(bfrag8*)&wl[orow][cs * 8] = *(const bfrag8*)(wlo_g + orow * CIN + c0 + cs * 8);
            }
        }
        __syncthreads();
        #pragma unroll
        for (int ks = 0; ks < 2; ++ks) {
            bfrag8 ah[2], al[2];
            #pragma unroll
            for (int s = 0; s < 2; ++s) {
                ah[s] = *(const bfrag8*)&xh[wn * 32 + s * 16 + lr][ks * 32 + lk * 8];
                al[s] = *(const bfrag8*)&xl[wn * 32 + s * 16 + lr][ks * 32 + lk * 8];
            }
            #pragma unroll
            for (int so = 0; so < 3; ++so) {
                bfrag8 bh8 = *(const bfrag8*)&wh[wo * 48 + so * 16 + lr][ks * 32 + lk * 8];
                bfrag8 bl8 = *(const bfrag8*)&wl[wo * 48 + so * 16 + lr][ks * 32 + lk * 8];
                #pragma unroll
                for (int sn = 0; sn < 2; ++sn) {
                    acc[sn][so] = __builtin_amdgcn_mfma_f32_16x16x32_bf16(ah[sn], bh8, acc[sn][so], 0, 0, 0);
                    acc[sn][so] = __builtin_amdgcn_mfma_f32_16x16x32_bf16(ah[sn], bl8, acc[sn][so], 0, 0, 0);
                    acc[sn][so] = __builtin_amdgcn_mfma_f32_16x16x32_bf16(al[sn], bh8, acc[sn][so], 0, 0, 0);
                }
            }
        }
        __syncthreads();
    }

    // ---- epilogue (wbuf aliased: g,h tile + reduce scratch) ----
    float (*mls)[136] = (float(*)[136])wbuf;            // [64 n][128 c'] 34.8 KB
    float (*tred)[64] = (float(*)[64])(wbuf + 36864);   // [8][64] 2 KB
    float* v0ls       = (float*)xh;                     // 64 f32 (aliases xh)

    #pragma unroll
    for (int so = 0; so < 3; ++so) {
        const int o = wo * 48 + so * 16 + lr;
        const float bias = beff[o];
        const bool rl = (o < 128);   // relu on f,g only
        #pragma unroll
        for (int sn = 0; sn < 2; ++sn)
            #pragma unroll
            for (int r = 0; r < 4; ++r) {
                const int nn = wn * 32 + sn * 16 + lk * 4 + r;
                const int n = n0 + nn;
                float v = acc[sn][so][r] + bias;
                if (rl) v = fmaxf(v, 0.0f);
                if (o < 128) fghT[((size_t)(b * HW) + n) * 128 + o] = v;
                if (o < 64) {
                    unsigned short hi, lo; split_bf(v, hi, lo);
                    fhi[((size_t)(b * HW) + n) * MID + o] = hi;
                    flo[((size_t)(b * HW) + n) * MID + o] = lo;
                }
                if (o >= 64) mls[nn][o - 64] = v;   // g cols 0..63, h cols 64..127
            }
    }
    if (tid < 64) v0ls[tid] = v0[(size_t)b * HW + n0 + tid];
    __syncthreads();

    {   // t partials
        const int c = tid & 63, ng = tid >> 6;
        float tp = 0.f;
        #pragma unroll
        for (int i = 0; i < 8; ++i) {
            const int nn = ng * 8 + i;
            tp = fmaf(mls[nn][c], v0ls[nn], tp);
        }
        tred[ng][c] = tp;
    }
    {   // M partials: mpart[b][nb][cp][cc]
        const int tcp = tid >> 4, tc = tid & 15;
        const int cp = tcp * 2, cc = tc * 4;
        float macc[2][4];
        #pragma unroll
        for (int i = 0; i < 2; ++i)
            #pragma unroll
            for (int j = 0; j < 4; ++j) macc[i][j] = 0.f;
        for (int nn = 0; nn < 64; ++nn) {
            const float g0 = mls[nn][cp], g1 = mls[nn][cp + 1];
            const float h0 = mls[nn][64 + cc + 0], h1 = mls[nn][64 + cc + 1];
            const float h2 = mls[nn][64 + cc + 2], h3 = mls[nn][64 + cc + 3];
            macc[0][0] = fmaf(g0, h0, macc[0][0]); macc[0][1] = fmaf(g0, h1, macc[0][1]);
            macc[0][2] = fmaf(g0, h2, macc[0][2]); macc[0][3] = fmaf(g0, h3, macc[0][3]);
            macc[1][0] = fmaf(g1, h0, macc[1][0]); macc[1][1] = fmaf(g1, h1, macc[1][1]);
            macc[1][2] = fmaf(g1, h2, macc[1][2]); macc[1][3] = fmaf(g1, h3, macc[1][3]);
        }
        const size_t mpb = ((size_t)(b * 64 + nb) * 64) * 64;
        *(float4*)&mpart[mpb + (size_t)(cp + 0) * 64 + cc] =
            make_float4(macc[0][0], macc[0][1], macc[0][2], macc[0][3]);
        *(float4*)&mpart[mpb + (size_t)(cp + 1) * 64 + cc] =
            make_float4(macc[1][0], macc[1][1], macc[1][2], macc[1][3]);
    }
    __syncthreads();
    if (tid < 64) {
        float s = 0.f;
        #pragma unroll
        for (int g = 0; g < 8; ++g) s += tred[g][tid];
        tpart[((size_t)(b * 64) + nb) * 64 + tid] = s;
    }
}

// K2: reduce tpart -> t; vu = f.t for 64 n; per-block partials of nsq and fgvu. Grid (64, NB).
__launch_bounds__(256)
__global__ void k_vfg(const float* __restrict__ fghT, const float* __restrict__ tpart,
                      float* __restrict__ fgvu_part, float* __restrict__ nsq_part) {
    __shared__ float tred4[4][64];
    __shared__ float ts[64];
    __shared__ float vuls[64];
    __shared__ float red2[8][128];
    __shared__ float rs[4];
    const int chunk = blockIdx.x, b = blockIdx.y, n0 = chunk * 64;
    const int tid = threadIdx.x;
    {   // reduce t partials (64 nb)
        const int c = tid & 63, grp = tid >> 6;
        float s = 0.f;
        #pragma unroll
        for (int i = 0; i < 16; ++i)
            s += tpart[((size_t)(b * 64) + grp * 16 + i) * 64 + c];
        tred4[grp][c] = s;
    }
    __syncthreads();
    if (tid < 64) ts[tid] = tred4[0][tid] + tred4[1][tid] + tred4[2][tid] + tred4[3][tid];
    __syncthreads();
    // phase 1: vu for 64 n (4 lanes per n), single pass
    const int nl = tid >> 2, q = tid & 3;
    float mynsq = 0.f;
    {
        const int n = n0 + nl;
        const float* p = fghT + ((size_t)(b * HW) + n) * 128 + q * 16;
        float a = 0.f;
        #pragma unroll
        for (int u = 0; u < 4; ++u) {
            float4 fv = *(const float4*)(p + u * 4);
            a = fmaf(fv.x, ts[q * 16 + u * 4 + 0], a);
            a = fmaf(fv.y, ts[q * 16 + u * 4 + 1], a);
            a = fmaf(fv.z, ts[q * 16 + u * 4 + 2], a);
            a = fmaf(fv.w, ts[q * 16 + u * 4 + 3], a);
        }
        a += __shfl_xor(a, 1);
        a += __shfl_xor(a, 2);
        if (q == 0) { vuls[nl] = a; mynsq = a * a; }
    }
    {   // nsq partial (barrier also publishes vuls)
        float s = mynsq;
        #pragma unroll
        for (int off = 32; off > 0; off >>= 1) s += __shfl_down(s, off);
        if ((tid & 63) == 0) rs[tid >> 6] = s;
        __syncthreads();
        if (tid == 0) nsq_part[b * 64 + chunk] = rs[0] + rs[1] + rs[2] + rs[3];
    }
    // phase 2: fgvu partials
    const int rq = tid & 31, ng2 = tid >> 5;
    float a2[4] = {0.f, 0.f, 0.f, 0.f};
    #pragma unroll
    for (int it = 0; it < 8; ++it) {
        const int ni = ng2 + 8 * it;
        float4 fv = *(const float4*)(fghT + ((size_t)(b * HW) + n0 + ni) * 128 + rq * 4);
        const float vv = vuls[ni];
        a2[0] = fmaf(fv.x, vv, a2[0]); a2[1] = fmaf(fv.y, vv, a2[1]);
        a2[2] = fmaf(fv.z, vv, a2[2]); a2[3] = fmaf(fv.w, vv, a2[3]);
    }
    #pragma unroll
    for (int i = 0; i < 4; ++i) red2[ng2][rq * 4 + i] = a2[i];
    __syncthreads();
    if (tid < 128) {
        float s = 0.f;
        #pragma unroll
        for (int g = 0; g < 8; ++g) s += red2[g][tid];
        fgvu_part[(size_t)(b * 64 + chunk) * 128 + tid] = s;
    }
}

// K3: per block (4 cp rows, b): Mc = sum_nb mpart; s = (f.vu . g.vu)/nsq; w2 = (1/s) Wv M^T. Grid (16, NB).
__launch_bounds__(256)
__global__ void k_w2s(const float* __restrict__ Wv, const float* __restrict__ mpart,
                      const float* __restrict__ fgvu_part, const float* __restrict__ nsq_part,
                      unsigned short* __restrict__ w2hi, unsigned short* __restrict__ w2lo) {
    __shared__ float Mc[4][64];
    __shared__ float svs;
    const int cp0 = blockIdx.x * 4, b = blockIdx.y;
    const int tid = threadIdx.x;
    {   // reduce 64 nb-partials for rows cp0..cp0+3 (one output per thread)
        const int c = tid & 63, r = tid >> 6;
        float s = 0.f;
        for (int nb = 0; nb < 64; ++nb)
            s += mpart[((size_t)(b * 64 + nb) * 64 + cp0 + r) * 64 + c];
        Mc[r][c] = s;
    }
    if (tid < 64) {
        float fv = 0.f, gv = 0.f;
        for (int ch = 0; ch < 64; ++ch) {
            fv += fgvu_part[(size_t)(b * 64 + ch) * 128 + tid];
            gv += fgvu_part[(size_t)(b * 64 + ch) * 128 + 64 + tid];
        }
        float ns = nsq_part[b * 64 + tid];
        float num = fv * gv;
        #pragma unroll
        for (int off = 32; off > 0; off >>= 1) {
            num += __shfl_down(num, off);
            ns  += __shfl_down(ns, off);
        }
        if (tid == 0) svs = num / ns;
    }
    __syncthreads();
    const float inv_s = 1.0f / svs;
    const int o = tid;
    float wv[64];
    #pragma unroll
    for (int u = 0; u < 16; ++u) {
        float4 w4 = *(const float4*)(Wv + o * MID + u * 4);
        wv[u * 4 + 0] = w4.x; wv[u * 4 + 1] = w4.y; wv[u * 4 + 2] = w4.z; wv[u * 4 + 3] = w4.w;
    }
    unsigned short rh[4] __attribute__((aligned(8)));
    unsigned short rl[4] __attribute__((aligned(8)));
    #pragma unroll
    for (int j = 0; j < 4; ++j) {
        float a = 0.f;
        #pragma unroll
        for (int c = 0; c < 64; ++c) a = fmaf(wv[c], Mc[j][c], a);
        split_bf(a * inv_s, rh[j], rl[j]);
    }
    const size_t base = ((size_t)(b * CIN) + o) * MID + cp0;
    *(svec4*)(w2hi + base) = *(const svec4*)rh;
    *(svec4*)(w2lo + base) = *(const svec4*)rl;
}

// K4: out[b][o][n] = x + bv[o] + sum_cp w2[o][cp] f[n][cp]   via split-bf16 MFMA, D[o][n]
__launch_bounds__(256)
__global__ void k_out(const float* __restrict__ x,
                      const unsigned short* __restrict__ fhi, const unsigned short* __restrict__ flo,
                      const unsigned short* __restrict__ w2hi, const unsigned short* __restrict__ w2lo,
                      const float* __restrict__ bv, float* __restrict__ out) {
    __shared__ unsigned short fh[64][72], fl[64][72], wh[64][72], wl[64][72];
    const int n0 = blockIdx.x * 64;
    const int o0 = blockIdx.y * 64;
    const int b  = blockIdx.z;
    const int tid = threadIdx.x, l = tid & 63, w = tid >> 6;
    const int wo = w >> 1, wn = w & 1;
    const int lr = l & 15, lk = l >> 4;
    #pragma unroll
    for (int i = 0; i < 2; ++i) {
        int ch = tid + i * 256;
        int row = ch >> 3, cs = ch & 7;
        const size_t fsrc = ((size_t)(b * HW) + n0 + row) * MID + cs * 8;
        const size_t wsrc = ((size_t)(b * CIN) + o0 + row) * MID + cs * 8;
        *(bfrag8*)&fh[row][cs * 8] = *(const bfrag8*)(fhi + fsrc);
        *(bfrag8*)&fl[row][cs * 8] = *(const bfrag8*)(flo + fsrc);
        *(bfrag8*)&wh[row][cs * 8] = *(const bfrag8*)(w2hi + wsrc);
        *(bfrag8*)&wl[row][cs * 8] = *(const bfrag8*)(w2lo + wsrc);
    }
    __syncthreads();
    facc4 acc[2][2];   // [so][sn]
    #pragma unroll
    for (int i = 0; i < 2; ++i)
        #pragma unroll
        for (int j = 0; j < 2; ++j) acc[i][j] = (facc4){0.f, 0.f, 0.f, 0.f};
    #pragma unroll
    for (int ks = 0; ks < 2; ++ks) {
        bfrag8 ah[2], al[2], bh[2], bl[2];
        #pragma unroll
        for (int s = 0; s < 2; ++s) {
            ah[s] = *(const bfrag8*)&wh[wo * 32 + s * 16 + lr][ks * 32 + lk * 8];
            al[s] = *(const bfrag8*)&wl[wo * 32 + s * 16 + lr][ks * 32 + lk * 8];
            bh[s] = *(const bfrag8*)&fh[wn * 32 + s * 16 + lr][ks * 32 + lk * 8];
            bl[s] = *(const bfrag8*)&fl[wn * 32 + s * 16 + lr][ks * 32 + lk * 8];
        }
        #pragma unroll
        for (int so = 0; so < 2; ++so)
            #pragma unroll
            for (int sn = 0; sn < 2; ++sn) {
                acc[so][sn] = __builtin_amdgcn_mfma_f32_16x16x32_bf16(ah[so], bh[sn], acc[so][sn], 0, 0, 0);
                acc[so][sn] = __builtin_amdgcn_mfma_f32_16x16x32_bf16(ah[so], bl[sn], acc[so][sn], 0, 0, 0);
                acc[so][sn] = __builtin_amdgcn_mfma_f32_16x16x32_bf16(al[so], bh[sn], acc[so][sn], 0, 0, 0);
            }
    }
    #pragma unroll
    for (int so = 0; so < 2; ++so)
        #pragma unroll
        for (int r = 0; r < 4; ++r) {
            const int o = o0 + wo * 32 + so * 16 + lk * 4 + r;
            const float bias = bv[o];
            #pragma unroll
            for (int sn = 0; sn < 2; ++sn) {
                const int n = n0 + wn * 32 + sn * 16 + lr;
                const size_t idx = ((size_t)(b * CIN) + o) * HW + n;
                out[idx] = x[idx] + bias + acc[so][sn][r];
            }
        }
}

extern "C" void kernel_launch(void* const* d_in, const int* in_sizes, int n_in,
                              void* d_out, int out_size, void* d_ws, size_t ws_size,
                              hipStream_t stream) {
    const float* x   = (const float*)d_in[0];
    const float* Wf  = (const float*)d_in[1];
    const float* bf  = (const float*)d_in[2];
    const float* gaf = (const float*)d_in[3];
    const float* bef = (const float*)d_in[4];
    const float* mef = (const float*)d_in[5];
    const float* vaf = (const float*)d_in[6];
    const float* Wg  = (const float*)d_in[7];
    const float* bg  = (const float*)d_in[8];
    const float* gag = (const float*)d_in[9];
    const float* beg = (const float*)d_in[10];
    const float* meg = (const float*)d_in[11];
    const float* vag = (const float*)d_in[12];
    const float* Wh  = (const float*)d_in[13];
    const float* bh  = (const float*)d_in[14];
    const float* Wv  = (const float*)d_in[15];
    const float* bv  = (const float*)d_in[16];
    const float* v0  = (const float*)d_in[17];
    float* out = (float*)d_out;
    char* ws = (char*)d_ws;

    float*          fghT = (float*)(ws + OFF_FGHT);
    unsigned short* fhi  = (unsigned short*)(ws + OFF_FHI);
    unsigned short* flo  = (unsigned short*)(ws + OFF_FLO);
    unsigned short* whi  = (unsigned short*)(ws + OFF_WHI);
    unsigned short* wlo  = (unsigned short*)(ws + OFF_WLO);
    float*          beff = (float*)(ws + OFF_BEFF);
    unsigned short* w2hi = (unsigned short*)(ws + OFF_W2HI);
    unsigned short* w2lo = (unsigned short*)(ws + OFF_W2LO);
    float*          mpart= (float*)(ws + OFF_MPART);
    float*          tpart= (float*)(ws + OFF_TPART);
    float*          fgvup= (float*)(ws + OFF_FGVUP);
    float*          nsqp = (float*)(ws + OFF_NSQP);

    k_weff<<<192, CIN, 0, stream>>>(Wf, bf, gaf, bef, mef, vaf,
                                    Wg, bg, gag, beg, meg, vag,
                                    Wh, bh, whi, wlo, beff);
    k_fgh2<<<dim3(HW / 64, NB), 512, 0, stream>>>(x, whi, wlo, beff, v0,
                                                  fghT, fhi, flo, tpart, mpart);
    k_vfg <<<dim3(64, NB), 256, 0, stream>>>(fghT, tpart, fgvup, nsqp);
    k_w2s <<<dim3(16, NB), 256, 0, stream>>>(Wv, mpart, fgvup, nsqp, w2hi, w2lo);
    k_out <<<dim3(HW / 64, CIN / 64, NB), 256, 0, stream>>>(x, fhi, flo, w2hi, w2lo, bv, out);
}